// Round 1
// 429.557 us; speedup vs baseline: 1.0369x; 1.0369x over previous
//
#include <hip/hip_runtime.h>
#include <hip/hip_bf16.h>
#include <math.h>

// Problem constants: B=4, N=4096, k=32, Cin=64, Cout=64, M=8, hidden=16
#define PB 4
#define PN 4096
#define PK 32
#define NKP (PN * PK)              // 131072 points per batch (2^17)
#define PTOT (PB * NKP)            // 524288 total points
#define CIN 64
#define COUT 64
#define PM 8
#define HID 16
#define EPS 1e-5f

// ws float layout (unchanged)
#define WS_MOM 0            // 14 slots x stride 16 floats = [0..224)
#define WS_A1 240           // 16: BN1 folded scale
#define WS_B1 256           // 16: BN1 folded shift
#define WS_A2 288           // 64: BN2 folded scale
#define WS_B2 352           // 64: BN2 folded shift
#define WS_PSUM 416         // 32 slots x 64: out channel sum partials
#define WS_PSQ 2464         // 32 slots x 64: out channel sumsq partials
#define WS_ZERO_FLOATS 4512
#define WS_WBT 4608         // bf16 wbT[512][64] as ushort (32768 entries, 64 KB)

typedef __attribute__((ext_vector_type(8))) short short8;
typedef __attribute__((ext_vector_type(4))) float float4v;
typedef unsigned int uint32;
typedef unsigned short ushort16;

// fp32 -> bf16 with round-half-up (cheap: add 0x8000, take hi16)
static __device__ __forceinline__ ushort16 f2bf(float v) {
  uint32 u = __builtin_bit_cast(uint32, v);
  return (ushort16)((u + 0x8000u) >> 16);
}

// async 16B global->LDS (fire-and-forget; drained by __syncthreads)
static __device__ __forceinline__ void gload_lds16(const float* g, float* l) {
  __builtin_amdgcn_global_load_lds(
      (const __attribute__((address_space(1))) void*)g,
      (__attribute__((address_space(3))) void*)l, 16, 0, 0);
}

// ---------------------------------------------------------------------------
// Kernel 1 (fused): blocks [0,MOMB) -> xyz moments; blocks [MOMB,MOMB+128) ->
// wb transpose to bf16. Saves one launch; MOMB=256 uses the whole chip.
// ---------------------------------------------------------------------------
#define MOMB 256
__global__ __launch_bounds__(256) void k_pre(const float* __restrict__ gx,
                                             const float* __restrict__ wb,
                                             float* __restrict__ ws) {
  if (blockIdx.x >= MOMB) {
    // wbT: (64x512 fp32) -> bf16 [col=512][ci=64]
    int idx = (int)(blockIdx.x - MOMB) * 256 + threadIdx.x;  // 0..32767
    int ci = idx >> 9;
    int col = idx & 511;
    ((ushort16*)(ws + WS_WBT))[col * 64 + ci] = f2bf(wb[idx]);
    return;
  }
  float s[14];
#pragma unroll
  for (int i = 0; i < 14; ++i) s[i] = 0.f;
  int tid = blockIdx.x * 256 + threadIdx.x;  // 0..65535
  const int nth = MOMB * 256;
  for (int p = tid; p < PTOT; p += nth) {
    int b = p >> 17;
    int r = p & (NKP - 1);
    const float* base = gx + (size_t)b * 3 * NKP + r;
    float v[4];
    v[0] = base[0];
    v[1] = base[NKP];
    v[2] = base[2 * NKP];
    v[3] = sqrtf(v[0] * v[0] + v[1] * v[1] + v[2] * v[2]);
#pragma unroll
    for (int j = 0; j < 4; ++j) s[j] += v[j];
    int idx = 4;
#pragma unroll
    for (int j = 0; j < 4; ++j)
#pragma unroll
      for (int l = j; l < 4; ++l) s[idx++] += v[j] * v[l];
  }
#pragma unroll
  for (int i = 0; i < 14; ++i) {
    float x = s[i];
#pragma unroll
    for (int off = 32; off > 0; off >>= 1) x += __shfl_down(x, off, 64);
    s[i] = x;
  }
  __shared__ float red[4][14];
  int wave = threadIdx.x >> 6;
  if ((threadIdx.x & 63) == 0) {
#pragma unroll
    for (int i = 0; i < 14; ++i) red[wave][i] = s[i];
  }
  __syncthreads();
  if (threadIdx.x < 14) {
    float v = red[0][threadIdx.x] + red[1][threadIdx.x] +
              red[2][threadIdx.x] + red[3][threadIdx.x];
    atomicAdd(&ws[WS_MOM + threadIdx.x * 16], v);
  }
}

// ---------------------------------------------------------------------------
// Kernel 2: fold BN1 into alpha1/beta1 from the 14 moments (unchanged).
// ---------------------------------------------------------------------------
__global__ void k_finalize1(const float* __restrict__ ws,
                            const float* __restrict__ w1,
                            const float* __restrict__ g1,
                            const float* __restrict__ b1,
                            float* __restrict__ out_ws) {
  int c = threadIdx.x;
  if (c >= HID) return;
  const float invP = 1.f / (float)PTOT;
  float mu[4];
#pragma unroll
  for (int j = 0; j < 4; ++j) mu[j] = ws[WS_MOM + j * 16] * invP;
  float S[4][4];
  int idx = 4;
#pragma unroll
  for (int j = 0; j < 4; ++j)
#pragma unroll
    for (int l = j; l < 4; ++l) {
      float v = ws[WS_MOM + idx * 16] * invP;
      ++idx;
      S[j][l] = v;
      S[l][j] = v;
    }
  float w[4];
#pragma unroll
  for (int j = 0; j < 4; ++j) w[j] = w1[c * 4 + j];
  float mean = 0.f;
#pragma unroll
  for (int j = 0; j < 4; ++j) mean += w[j] * mu[j];
  float Et2 = 0.f;
#pragma unroll
  for (int j = 0; j < 4; ++j)
#pragma unroll
    for (int l = 0; l < 4; ++l) Et2 += w[j] * w[l] * S[j][l];
  float var = Et2 - mean * mean;
  float a = g1[c] * rsqrtf(var + EPS);
  out_ws[WS_A1 + c] = a;
  out_ws[WS_B1 + c] = b1[c] - a * mean;
}

// ---------------------------------------------------------------------------
// Kernel 3: main MFMA kernel, restructured.
//  - mfma(wb_frag, feat_frag): D = out^T tile (row=channel, col=point) so the
//    C-write goes straight from accumulators to global (no outst LDS, -1
//    barrier). rt0+rt1 halves of each channel row merge to full 128B lines.
//  - feat staged fp32 via global_load_lds width-16 (fire-and-forget, no VGPR
//    round-trip, no f2bf at stage time). Scaling now happens on full-precision
//    fp32 with a single bf16 rounding.
//  - p-bit4 XOR swizzle keyed on ci-bit3, applied to BOTH the global source
//    address and the ds_read address -> 2-way (free) LDS bank aliasing.
//  LDS = 32KB fl + 4KB scl + 2KB stats = 38,912B -> 4 blocks/CU.
// ---------------------------------------------------------------------------
#define PPB 128   // points per block
#define SM_FL 0       // [64][128] fp32 feat tile, [ci][p^swz]
#define SM_SCL 8192   // [128][8] scores
#define SM_SSTAT 9216 // [4][64]
#define SM_QSTAT 9472 // [4][64]

__global__ __launch_bounds__(256, 4) void k_main_mfma(
    const float* __restrict__ gx, const float* __restrict__ feat,
    const float* __restrict__ w1, const float* __restrict__ w2,
    const float* __restrict__ b2, const ushort16* __restrict__ wbt,
    float* __restrict__ ws, float* __restrict__ out) {
  __shared__ float smem[9728];

  const int t = threadIdx.x;
  const int pblk = blockIdx.x * PPB;
  const int b = pblk >> 17;
  const int r0 = pblk & (NKP - 1);

  // ---- issue async feat staging FIRST so HBM/L3 latency hides under ScoreNet
  {
    const float* fb = feat + (size_t)b * CIN * NKP + r0;
    int l = t & 63;
    int wv = t >> 6;
#pragma unroll
    for (int i = 0; i < 8; ++i) {
      int chunk = wv * 8 + i;                 // 0..31, 1KB of LDS each
      int ci = chunk * 2 + (l >> 5);          // 2 ci-rows per chunk
      int swz = (ci >> 3) & 1;
      int poff = ((l & 31) << 2) ^ (swz << 4);  // inverse-swizzled source
      gload_lds16(fb + (size_t)ci * NKP + poff, &smem[SM_FL + chunk * 256]);
    }
  }

  // ---- ScoreNet for the block's 128 points (threads 0..127)
  if (t < PPB) {
    int r = r0 + t;
    const float* gb = gx + (size_t)b * 3 * NKP + r;
    float x = gb[0], y = gb[NKP], z = gb[2 * NKP];
    float ed = sqrtf(x * x + y * y + z * z);
    float h[HID];
#pragma unroll
    for (int c = 0; c < HID; ++c) {
      float tv = w1[c * 4 + 0] * x + w1[c * 4 + 1] * y + w1[c * 4 + 2] * z +
                 w1[c * 4 + 3] * ed;
      h[c] = fmaxf(ws[WS_A1 + c] * tv + ws[WS_B1 + c], 0.f);
    }
    float s[PM];
#pragma unroll
    for (int m = 0; m < PM; ++m) {
      float a = b2[m];
#pragma unroll
      for (int c = 0; c < HID; ++c) a += w2[m * HID + c] * h[c];
      s[m] = a;
    }
    float mx = s[0];
#pragma unroll
    for (int m = 1; m < PM; ++m) mx = fmaxf(mx, s[m]);
    float esum = 0.f;
#pragma unroll
    for (int m = 0; m < PM; ++m) {
      s[m] = __expf(s[m] - mx);
      esum += s[m];
    }
    float inv = 1.f / (1.f + esum);
#pragma unroll
    for (int m = 0; m < PM; ++m) smem[SM_SCL + t * 8 + m] = s[m] * inv;
  }

  __syncthreads();  // drains vmcnt -> fl complete; scl complete

  const int w = t >> 6;
  const int L = t & 63;
  const int l16 = L & 15;
  const int q4 = L >> 4;
  const int prow = w * 32;

  // ---- preload feat fragments (fp32) + scores
  float ff[2][2][8];  // [rowtile][kstep][elem]
#pragma unroll
  for (int rt = 0; rt < 2; ++rt) {
    int p = prow + rt * 16 + l16;
    int psw = p ^ ((q4 & 1) << 4);  // matches source swizzle
#pragma unroll
    for (int ks = 0; ks < 2; ++ks) {
#pragma unroll
      for (int j = 0; j < 8; ++j) {
        int ci = ks * 32 + q4 * 8 + j;
        ff[rt][ks][j] = smem[SM_FL + ci * 128 + psw];
      }
    }
  }
  float4v scf[2][2];  // [rowtile][half]: 8 scores for this lane's point
#pragma unroll
  for (int rt = 0; rt < 2; ++rt) {
    int p = prow + rt * 16 + l16;
    const float4v* sp = (const float4v*)&smem[SM_SCL + p * 8];
    scf[rt][0] = sp[0];
    scf[rt][1] = sp[1];
  }

  float4v acc[2][4];
#pragma unroll
  for (int rt = 0; rt < 2; ++rt)
#pragma unroll
    for (int ct = 0; ct < 4; ++ct) acc[rt][ct] = (float4v)0.f;

  // ---- m loop: scale feat (B operand) by sc[p][m], MFMA against wbT m-slice
#pragma unroll
  for (int m = 0; m < PM; ++m) {
    short8 bf[2][4];  // [kstep][coltile] : A operand (rows = out channels)
#pragma unroll
    for (int ks = 0; ks < 2; ++ks)
#pragma unroll
      for (int ct = 0; ct < 4; ++ct) {
        int col = m * 64 + ct * 16 + l16;
        bf[ks][ct] = *(const short8*)(wbt + col * 64 + ks * 32 + q4 * 8);
      }
#pragma unroll
    for (int rt = 0; rt < 2; ++rt) {
      float sm = scf[rt][m >> 2][m & 3];
#pragma unroll
      for (int ks = 0; ks < 2; ++ks) {
        union { short8 v; uint32 u[4]; } au;
#pragma unroll
        for (int e = 0; e < 4; ++e) {
          uint32 u0 =
              __builtin_bit_cast(uint32, ff[rt][ks][2 * e] * sm) + 0x8000u;
          uint32 u1 =
              __builtin_bit_cast(uint32, ff[rt][ks][2 * e + 1] * sm) + 0x8000u;
          au.u[e] = __builtin_amdgcn_perm(u1, u0, 0x07060302u);
        }
        // swapped operands: D[row=channel][col=point]
#pragma unroll
        for (int ct = 0; ct < 4; ++ct)
          acc[rt][ct] = __builtin_amdgcn_mfma_f32_16x16x32_bf16(
              bf[ks][ct], au.v, acc[rt][ct], 0, 0, 0);
      }
    }
  }

  // ---- BN2 stats: lane holds out[c=ct*16+q4*4+r][p=l16]; reduce over 16
  // points with xor-shuffles inside each 16-lane group (rt pre-summed).
#pragma unroll
  for (int ct = 0; ct < 4; ++ct) {
#pragma unroll
    for (int r = 0; r < 4; ++r) {
      float v0 = acc[0][ct][r], v1 = acc[1][ct][r];
      float s = v0 + v1;
      float q = v0 * v0 + v1 * v1;
#pragma unroll
      for (int off = 1; off < 16; off <<= 1) {
        s += __shfl_xor(s, off, 64);
        q += __shfl_xor(q, off, 64);
      }
      if (l16 == 0) {
        smem[SM_SSTAT + w * 64 + ct * 16 + q4 * 4 + r] = s;
        smem[SM_QSTAT + w * 64 + ct * 16 + q4 * 4 + r] = q;
      }
    }
  }

  // ---- direct global write from accumulators: per store, 4x64B segments;
  // rt0+rt1 of a lane complete 128B lines which merge in L2.
  float* ob = out + (size_t)b * COUT * NKP + (r0 + prow);
#pragma unroll
  for (int rt = 0; rt < 2; ++rt)
#pragma unroll
    for (int ct = 0; ct < 4; ++ct)
#pragma unroll
      for (int r = 0; r < 4; ++r)
        ob[(size_t)(ct * 16 + q4 * 4 + r) * NKP + rt * 16 + l16] =
            acc[rt][ct][r];

  __syncthreads();

  // ---- block stats reduce -> spread atomics
  if (t < COUT) {
    float s = smem[SM_SSTAT + t] + smem[SM_SSTAT + 64 + t] +
              smem[SM_SSTAT + 128 + t] + smem[SM_SSTAT + 192 + t];
    float q = smem[SM_QSTAT + t] + smem[SM_QSTAT + 64 + t] +
              smem[SM_QSTAT + 128 + t] + smem[SM_QSTAT + 192 + t];
    int slot = blockIdx.x & 31;
    atomicAdd(&ws[WS_PSUM + slot * 64 + t], s);
    atomicAdd(&ws[WS_PSQ + slot * 64 + t], q);
  }
}

// ---------------------------------------------------------------------------
// Kernel 4: fold BN2 (reduce the 32 partial slots) (unchanged).
// ---------------------------------------------------------------------------
__global__ void k_finalize2(const float* __restrict__ ws,
                            const float* __restrict__ g_out,
                            const float* __restrict__ b_out,
                            float* __restrict__ out_ws) {
  int c = threadIdx.x;
  if (c >= COUT) return;
  float s = 0.f, q = 0.f;
  for (int sl = 0; sl < 32; ++sl) {
    s += ws[WS_PSUM + sl * 64 + c];
    q += ws[WS_PSQ + sl * 64 + c];
  }
  const float invP = 1.f / (float)PTOT;
  float mean = s * invP;
  float var = q * invP - mean * mean;
  float a = g_out[c] * rsqrtf(var + EPS);
  out_ws[WS_A2 + c] = a;
  out_ws[WS_B2 + c] = b_out[c] - a * mean;
}

// ---------------------------------------------------------------------------
// Kernel 5: in-place normalize + ReLU, grid-strided (4096 blocks x 8 float4).
// ---------------------------------------------------------------------------
#define NORMB 4096
__global__ __launch_bounds__(256) void k_norm(float* __restrict__ out,
                                              const float* __restrict__ ws) {
  size_t i4 = (size_t)blockIdx.x * 256 + threadIdx.x;
  const size_t stride = (size_t)NORMB * 256;
  float4* p = (float4*)out;
#pragma unroll
  for (int it = 0; it < 8; ++it, i4 += stride) {
    int c = (int)((i4 >> 15) & 63);  // elem = i4*4; c = (elem>>17)&63
    float a = ws[WS_A2 + c];
    float bb = ws[WS_B2 + c];
    float4 v = p[i4];
    v.x = fmaxf(a * v.x + bb, 0.f);
    v.y = fmaxf(a * v.y + bb, 0.f);
    v.z = fmaxf(a * v.z + bb, 0.f);
    v.w = fmaxf(a * v.w + bb, 0.f);
    p[i4] = v;
  }
}

extern "C" void kernel_launch(void* const* d_in, const int* in_sizes, int n_in,
                              void* d_out, int out_size, void* d_ws,
                              size_t ws_size, hipStream_t stream) {
  const float* gx = (const float*)d_in[0];
  const float* feat = (const float*)d_in[1];
  const float* w1 = (const float*)d_in[2];
  const float* g1 = (const float*)d_in[3];
  const float* b1 = (const float*)d_in[4];
  const float* w2 = (const float*)d_in[5];
  const float* b2 = (const float*)d_in[6];
  const float* wb = (const float*)d_in[7];
  const float* g_out = (const float*)d_in[8];
  const float* b_out = (const float*)d_in[9];
  float* out = (float*)d_out;
  float* ws = (float*)d_ws;
  ushort16* wbt = (ushort16*)(ws + WS_WBT);

  (void)in_sizes; (void)n_in; (void)out_size; (void)ws_size;

  hipMemsetAsync(d_ws, 0, WS_ZERO_FLOATS * sizeof(float), stream);

  k_pre<<<MOMB + 128, 256, 0, stream>>>(gx, wb, ws);
  k_finalize1<<<1, 64, 0, stream>>>(ws, w1, g1, b1, ws);
  k_main_mfma<<<PTOT / PPB, 256, 0, stream>>>(gx, feat, w1, w2, b2, wbt, ws,
                                              out);
  k_finalize2<<<1, 64, 0, stream>>>(ws, g_out, b_out, ws);
  k_norm<<<NORMB, 256, 0, stream>>>(out, ws);
}

// Round 2
// 365.664 us; speedup vs baseline: 1.2181x; 1.1747x over previous
//
#include <hip/hip_runtime.h>
#include <hip/hip_bf16.h>
#include <math.h>

// Problem constants: B=4, N=4096, k=32, Cin=64, Cout=64, M=8, hidden=16
#define PB 4
#define PN 4096
#define PK 32
#define NKP (PN * PK)              // 131072 points per batch (2^17)
#define PTOT (PB * NKP)            // 524288 total points
#define CIN 64
#define COUT 64
#define PM 8
#define HID 16
#define EPS 1e-5f

// ws float layout (unchanged)
#define WS_MOM 0            // 14 slots x stride 16 floats = [0..224)
#define WS_A1 240           // 16: BN1 folded scale
#define WS_B1 256           // 16: BN1 folded shift
#define WS_A2 288           // 64: BN2 folded scale
#define WS_B2 352           // 64: BN2 folded shift
#define WS_PSUM 416         // 32 slots x 64: out channel sum partials
#define WS_PSQ 2464         // 32 slots x 64: out channel sumsq partials
#define WS_ZERO_FLOATS 4512
#define WS_WBT 4608         // bf16 wbT[512][64] as ushort (32768 entries, 64 KB)

typedef __attribute__((ext_vector_type(8))) short short8;
typedef __attribute__((ext_vector_type(4))) float float4v;
typedef __attribute__((ext_vector_type(4))) unsigned int uint4v;
typedef unsigned int uint32;
typedef unsigned short ushort16;

// fp32 -> bf16 with round-half-up (cheap: add 0x8000, take hi16)
static __device__ __forceinline__ ushort16 f2bf(float v) {
  uint32 u = __builtin_bit_cast(uint32, v);
  return (ushort16)((u + 0x8000u) >> 16);
}

// async 16B global->LDS (fire-and-forget; vmcnt-counted)
static __device__ __forceinline__ void gload_lds16(const float* g, float* l) {
  __builtin_amdgcn_global_load_lds(
      (const __attribute__((address_space(1))) void*)g,
      (__attribute__((address_space(3))) void*)l, 16, 0, 0);
}

// ---------------------------------------------------------------------------
// Kernel 1 (fused): blocks [0,MOMB) -> xyz moments; blocks [MOMB,MOMB+128) ->
// wb transpose to bf16.
// ---------------------------------------------------------------------------
#define MOMB 256
__global__ __launch_bounds__(256) void k_pre(const float* __restrict__ gx,
                                             const float* __restrict__ wb,
                                             float* __restrict__ ws) {
  if (blockIdx.x >= MOMB) {
    int idx = (int)(blockIdx.x - MOMB) * 256 + threadIdx.x;  // 0..32767
    int ci = idx >> 9;
    int col = idx & 511;
    ((ushort16*)(ws + WS_WBT))[col * 64 + ci] = f2bf(wb[idx]);
    return;
  }
  float s[14];
#pragma unroll
  for (int i = 0; i < 14; ++i) s[i] = 0.f;
  int tid = blockIdx.x * 256 + threadIdx.x;  // 0..65535
  const int nth = MOMB * 256;
  for (int p = tid; p < PTOT; p += nth) {
    int b = p >> 17;
    int r = p & (NKP - 1);
    const float* base = gx + (size_t)b * 3 * NKP + r;
    float v[4];
    v[0] = base[0];
    v[1] = base[NKP];
    v[2] = base[2 * NKP];
    v[3] = sqrtf(v[0] * v[0] + v[1] * v[1] + v[2] * v[2]);
#pragma unroll
    for (int j = 0; j < 4; ++j) s[j] += v[j];
    int idx = 4;
#pragma unroll
    for (int j = 0; j < 4; ++j)
#pragma unroll
      for (int l = j; l < 4; ++l) s[idx++] += v[j] * v[l];
  }
#pragma unroll
  for (int i = 0; i < 14; ++i) {
    float x = s[i];
#pragma unroll
    for (int off = 32; off > 0; off >>= 1) x += __shfl_down(x, off, 64);
    s[i] = x;
  }
  __shared__ float red[4][14];
  int wave = threadIdx.x >> 6;
  if ((threadIdx.x & 63) == 0) {
#pragma unroll
    for (int i = 0; i < 14; ++i) red[wave][i] = s[i];
  }
  __syncthreads();
  if (threadIdx.x < 14) {
    float v = red[0][threadIdx.x] + red[1][threadIdx.x] +
              red[2][threadIdx.x] + red[3][threadIdx.x];
    atomicAdd(&ws[WS_MOM + threadIdx.x * 16], v);
  }
}

// ---------------------------------------------------------------------------
// Kernel 2: fold BN1 into alpha1/beta1 from the 14 moments (unchanged).
// ---------------------------------------------------------------------------
__global__ void k_finalize1(const float* __restrict__ ws,
                            const float* __restrict__ w1,
                            const float* __restrict__ g1,
                            const float* __restrict__ b1,
                            float* __restrict__ out_ws) {
  int c = threadIdx.x;
  if (c >= HID) return;
  const float invP = 1.f / (float)PTOT;
  float mu[4];
#pragma unroll
  for (int j = 0; j < 4; ++j) mu[j] = ws[WS_MOM + j * 16] * invP;
  float S[4][4];
  int idx = 4;
#pragma unroll
  for (int j = 0; j < 4; ++j)
#pragma unroll
    for (int l = j; l < 4; ++l) {
      float v = ws[WS_MOM + idx * 16] * invP;
      ++idx;
      S[j][l] = v;
      S[l][j] = v;
    }
  float w[4];
#pragma unroll
  for (int j = 0; j < 4; ++j) w[j] = w1[c * 4 + j];
  float mean = 0.f;
#pragma unroll
  for (int j = 0; j < 4; ++j) mean += w[j] * mu[j];
  float Et2 = 0.f;
#pragma unroll
  for (int j = 0; j < 4; ++j)
#pragma unroll
    for (int l = 0; l < 4; ++l) Et2 += w[j] * w[l] * S[j][l];
  float var = Et2 - mean * mean;
  float a = g1[c] * rsqrtf(var + EPS);
  out_ws[WS_A1 + c] = a;
  out_ws[WS_B1 + c] = b1[c] - a * mean;
}

// ---------------------------------------------------------------------------
// Kernel 3: main MFMA kernel — channel-split waves, resident weights,
// post-MFMA scaling, 8-subtile double-buffered async pipeline.
//
//  - wave w owns out channels [16w,16w+16) for ALL 512 points of the block;
//    its wbt slice (16 x short8 = 64 VGPR) is loaded ONCE -> compute phase
//    has NO global loads, so counted vmcnt waits keep stage DMAs in flight.
//  - out = sum_m s_m[p] * (wb_m . f): MFMA on unscaled bf16 feat, scale
//    applied post-MFMA with 4 fma/lane per (m,rt). No per-m repack.
//  - feat staged fp32 via global_load_lds into 2 x [64ci][64p] buffers;
//    p-bit4 XOR swizzle keyed on ci-bit3 on BOTH source addr and ds_read.
//  - vmcnt(4) at subtile entry: correct under load-load in-order retirement
//    alone (4 = next subtile's in-flight stage loads; robust to store/spill
//    reordering). Raw s_barrier + sched_barrier(0) fences per rule 18/21.
//  LDS = 2*16KB bufs + 16KB scores = 48KB -> 3 blocks/CU.
// ---------------------------------------------------------------------------
#define PPB 512   // points per block
#define SUB 64    // points per subtile
#define NSUB 8
#define SM_SCL 8192  // float idx: scores SoA [m][512]

__global__ __launch_bounds__(256, 3) void k_main_mfma(
    const float* __restrict__ gx, const float* __restrict__ feat,
    const float* __restrict__ w1, const float* __restrict__ w2,
    const float* __restrict__ b2, const ushort16* __restrict__ wbt,
    float* __restrict__ ws, float* __restrict__ out) {
  __shared__ float smem[12288];  // 48 KB

  const int t = threadIdx.x;
  const int pblk = blockIdx.x * PPB;
  const int b = pblk >> 17;
  const int r0 = pblk & (NKP - 1);
  const int w = t >> 6;
  const int L = t & 63;
  const int l16 = L & 15;
  const int q4 = L >> 4;
  const int wchan = w * 16;

  // ---- resident weight fragments (issued first; retired by scorenet's wait)
  short8 bw[PM][2];
#pragma unroll
  for (int m = 0; m < PM; ++m)
#pragma unroll
    for (int ks = 0; ks < 2; ++ks)
      bw[m][ks] =
          *(const short8*)(wbt + (m * 64 + wchan + l16) * 64 + ks * 32 + q4 * 8);

  // ---- gx loads for scorenet (before stages so their wait leaves stages)
  float px[2], py[2], pz[2];
  {
    const float* gb = gx + (size_t)b * 3 * NKP + r0;
#pragma unroll
    for (int pp = 0; pp < 2; ++pp) {
      int p = t + pp * 256;
      px[pp] = gb[p];
      py[pp] = gb[NKP + p];
      pz[pp] = gb[2 * NKP + p];
    }
  }

  const float* fb = feat + (size_t)b * CIN * NKP + r0;
  // stage subtile s into buf[s&1]: 16 chunks x 1KB; wave issues 4.
  auto STAGE = [&](int s) {
    float* dst = &smem[(s & 1) * 4096];
    const float* src = fb + s * SUB;
#pragma unroll
    for (int i = 0; i < 4; ++i) {
      int chunk = w * 4 + i;
      int ci = chunk * 4 + (L >> 4);
      int sp = ((L & 15) << 2) ^ (((ci >> 3) & 1) << 4);  // inv-swizzled src
      gload_lds16(src + (size_t)ci * NKP + sp, dst + chunk * 256);
    }
  };

  STAGE(0);
  STAGE(1);

  // ---- ScoreNet: all 256 threads, 2 points each -> scl SoA [m][512]
#pragma unroll
  for (int pp = 0; pp < 2; ++pp) {
    float x = px[pp], y = py[pp], z = pz[pp];
    float ed = sqrtf(x * x + y * y + z * z);
    float h[HID];
#pragma unroll
    for (int c = 0; c < HID; ++c) {
      float tv = w1[c * 4 + 0] * x + w1[c * 4 + 1] * y + w1[c * 4 + 2] * z +
                 w1[c * 4 + 3] * ed;
      h[c] = fmaxf(ws[WS_A1 + c] * tv + ws[WS_B1 + c], 0.f);
    }
    float sc[PM];
#pragma unroll
    for (int m = 0; m < PM; ++m) {
      float a = b2[m];
#pragma unroll
      for (int c = 0; c < HID; ++c) a += w2[m * HID + c] * h[c];
      sc[m] = a;
    }
    float mx = sc[0];
#pragma unroll
    for (int m = 1; m < PM; ++m) mx = fmaxf(mx, sc[m]);
    float esum = 0.f;
#pragma unroll
    for (int m = 0; m < PM; ++m) {
      sc[m] = __expf(sc[m] - mx);
      esum += sc[m];
    }
    float inv = 1.f / (1.f + esum);
    int p = t + pp * 256;
#pragma unroll
    for (int m = 0; m < PM; ++m) smem[SM_SCL + m * 512 + p] = sc[m] * inv;
  }

  float sacc[4] = {0.f, 0.f, 0.f, 0.f};
  float qacc[4] = {0.f, 0.f, 0.f, 0.f};
  float* ob = out + (size_t)b * COUT * NKP + r0;

  auto COMPUTE = [&](int s) {
    const float* bufp = &smem[(s & 1) * 4096];
    // pack feat fragments to bf16 once (unscaled)
    uint4v ffb[4][2];
#pragma unroll
    for (int rt = 0; rt < 4; ++rt) {
      int p = rt * 16 + l16;
#pragma unroll
      for (int ks = 0; ks < 2; ++ks) {
        int cib = ks * 32 + q4 * 8;
        int psw = p ^ (((cib >> 3) & 1) << 4);
        const float* cp = bufp + cib * 64 + psw;
#pragma unroll
        for (int e = 0; e < 4; ++e) {
          uint32 u0 = __builtin_bit_cast(uint32, cp[(2 * e) * 64]) + 0x8000u;
          uint32 u1 = __builtin_bit_cast(uint32, cp[(2 * e + 1) * 64]) + 0x8000u;
          ffb[rt][ks][e] = __builtin_amdgcn_perm(u1, u0, 0x07060302u);
        }
      }
    }
    float4v fin[4];
#pragma unroll
    for (int rt = 0; rt < 4; ++rt) fin[rt] = (float4v)0.f;
#pragma unroll
    for (int m = 0; m < PM; ++m) {
      float sm[4];
#pragma unroll
      for (int rt = 0; rt < 4; ++rt)
        sm[rt] = smem[SM_SCL + m * 512 + s * SUB + rt * 16 + l16];  // broadcast
#pragma unroll
      for (int rt = 0; rt < 4; ++rt) {
        float4v g = (float4v)0.f;
        g = __builtin_amdgcn_mfma_f32_16x16x32_bf16(
            bw[m][0], __builtin_bit_cast(short8, ffb[rt][0]), g, 0, 0, 0);
        g = __builtin_amdgcn_mfma_f32_16x16x32_bf16(
            bw[m][1], __builtin_bit_cast(short8, ffb[rt][1]), g, 0, 0, 0);
#pragma unroll
        for (int r = 0; r < 4; ++r) fin[rt][r] += sm[rt] * g[r];
      }
    }
    // stores (only VMEM in compute) + stats accumulation
#pragma unroll
    for (int rt = 0; rt < 4; ++rt) {
      int p = s * SUB + rt * 16 + l16;
#pragma unroll
      for (int r = 0; r < 4; ++r) {
        float v = fin[rt][r];
        ob[(size_t)(wchan + q4 * 4 + r) * NKP + p] = v;
        sacc[r] += v;
        qacc[r] += v * v;
      }
    }
  };

#define ENTRY(VM_STR)                                    \
  asm volatile("s_waitcnt vmcnt(" VM_STR ")" ::: "memory"); \
  __builtin_amdgcn_s_barrier();                          \
  __builtin_amdgcn_sched_barrier(0);

#define EXITB()                                          \
  __builtin_amdgcn_sched_barrier(0);                     \
  __builtin_amdgcn_s_barrier();                          \
  __builtin_amdgcn_sched_barrier(0);

  // s = 0 (also drain scl ds_writes for all waves via lgkmcnt)
  asm volatile("s_waitcnt vmcnt(4) lgkmcnt(0)" ::: "memory");
  __builtin_amdgcn_s_barrier();
  __builtin_amdgcn_sched_barrier(0);
  COMPUTE(0);
  EXITB();
  STAGE(2);
  __builtin_amdgcn_sched_barrier(0);

  ENTRY("4") COMPUTE(1); EXITB(); STAGE(3); __builtin_amdgcn_sched_barrier(0);
  ENTRY("4") COMPUTE(2); EXITB(); STAGE(4); __builtin_amdgcn_sched_barrier(0);
  ENTRY("4") COMPUTE(3); EXITB(); STAGE(5); __builtin_amdgcn_sched_barrier(0);
  ENTRY("4") COMPUTE(4); EXITB(); STAGE(6); __builtin_amdgcn_sched_barrier(0);
  ENTRY("4") COMPUTE(5); EXITB(); STAGE(7); __builtin_amdgcn_sched_barrier(0);
  ENTRY("4") COMPUTE(6); EXITB();
  ENTRY("0") COMPUTE(7);

#undef ENTRY
#undef EXITB

  // ---- stats: reduce over the 16 l16-lanes of each q-group, then atomics.
#pragma unroll
  for (int off = 1; off < 16; off <<= 1) {
#pragma unroll
    for (int r = 0; r < 4; ++r) {
      sacc[r] += __shfl_xor(sacc[r], off, 64);
      qacc[r] += __shfl_xor(qacc[r], off, 64);
    }
  }
  if (l16 == 0) {
    int slot = blockIdx.x & 31;
#pragma unroll
    for (int r = 0; r < 4; ++r) {
      atomicAdd(&ws[WS_PSUM + slot * 64 + wchan + q4 * 4 + r], sacc[r]);
      atomicAdd(&ws[WS_PSQ + slot * 64 + wchan + q4 * 4 + r], qacc[r]);
    }
  }
}

// ---------------------------------------------------------------------------
// Kernel 4: fold BN2 (reduce the 32 partial slots) (unchanged).
// ---------------------------------------------------------------------------
__global__ void k_finalize2(const float* __restrict__ ws,
                            const float* __restrict__ g_out,
                            const float* __restrict__ b_out,
                            float* __restrict__ out_ws) {
  int c = threadIdx.x;
  if (c >= COUT) return;
  float s = 0.f, q = 0.f;
  for (int sl = 0; sl < 32; ++sl) {
    s += ws[WS_PSUM + sl * 64 + c];
    q += ws[WS_PSQ + sl * 64 + c];
  }
  const float invP = 1.f / (float)PTOT;
  float mean = s * invP;
  float var = q * invP - mean * mean;
  float a = g_out[c] * rsqrtf(var + EPS);
  out_ws[WS_A2 + c] = a;
  out_ws[WS_B2 + c] = b_out[c] - a * mean;
}

// ---------------------------------------------------------------------------
// Kernel 5: in-place normalize + ReLU, grid-strided.
// ---------------------------------------------------------------------------
#define NORMB 4096
__global__ __launch_bounds__(256) void k_norm(float* __restrict__ out,
                                              const float* __restrict__ ws) {
  size_t i4 = (size_t)blockIdx.x * 256 + threadIdx.x;
  const size_t stride = (size_t)NORMB * 256;
  float4* p = (float4*)out;
#pragma unroll
  for (int it = 0; it < 8; ++it, i4 += stride) {
    int c = (int)((i4 >> 15) & 63);  // elem = i4*4; c = (elem>>17)&63
    float a = ws[WS_A2 + c];
    float bb = ws[WS_B2 + c];
    float4 v = p[i4];
    v.x = fmaxf(a * v.x + bb, 0.f);
    v.y = fmaxf(a * v.y + bb, 0.f);
    v.z = fmaxf(a * v.z + bb, 0.f);
    v.w = fmaxf(a * v.w + bb, 0.f);
    p[i4] = v;
  }
}

extern "C" void kernel_launch(void* const* d_in, const int* in_sizes, int n_in,
                              void* d_out, int out_size, void* d_ws,
                              size_t ws_size, hipStream_t stream) {
  const float* gx = (const float*)d_in[0];
  const float* feat = (const float*)d_in[1];
  const float* w1 = (const float*)d_in[2];
  const float* g1 = (const float*)d_in[3];
  const float* b1 = (const float*)d_in[4];
  const float* w2 = (const float*)d_in[5];
  const float* b2 = (const float*)d_in[6];
  const float* wb = (const float*)d_in[7];
  const float* g_out = (const float*)d_in[8];
  const float* b_out = (const float*)d_in[9];
  float* out = (float*)d_out;
  float* ws = (float*)d_ws;
  ushort16* wbt = (ushort16*)(ws + WS_WBT);

  (void)in_sizes; (void)n_in; (void)out_size; (void)ws_size;

  hipMemsetAsync(d_ws, 0, WS_ZERO_FLOATS * sizeof(float), stream);

  k_pre<<<MOMB + 128, 256, 0, stream>>>(gx, wb, ws);
  k_finalize1<<<1, 64, 0, stream>>>(ws, w1, g1, b1, ws);
  k_main_mfma<<<PTOT / PPB, 256, 0, stream>>>(gx, feat, w1, w2, b2, wbt, ws,
                                              out);
  k_finalize2<<<1, 64, 0, stream>>>(ws, g_out, b_out, ws);
  k_norm<<<NORMB, 256, 0, stream>>>(out, ws);
}

// Round 3
// 346.965 us; speedup vs baseline: 1.2837x; 1.0539x over previous
//
#include <hip/hip_runtime.h>
#include <hip/hip_bf16.h>
#include <math.h>

// Problem constants: B=4, N=4096, k=32, Cin=64, Cout=64, M=8, hidden=16
#define PB 4
#define PN 4096
#define PK 32
#define NKP (PN * PK)              // 131072 points per batch (2^17)
#define PTOT (PB * NKP)            // 524288 total points
#define CIN 64
#define COUT 64
#define PM 8
#define HID 16
#define EPS 1e-5f

// ws float layout
#define WS_MOM 0            // 14 slots x stride 16 floats = [0..224)
#define WS_A2 288           // (unused now, kept for layout stability)
#define WS_PSUM 416         // 32 slots x 64: out channel sum partials
#define WS_PSQ 2464         // 32 slots x 64: out channel sumsq partials
#define WS_ZERO_FLOATS 4512
#define WS_WBT 4608         // bf16 wbT[512][64] as ushort (32768 entries, 64 KB)

typedef __attribute__((ext_vector_type(8))) short short8;
typedef __attribute__((ext_vector_type(4))) float float4v;
typedef __attribute__((ext_vector_type(4))) unsigned int uint4v;
typedef unsigned int uint32;
typedef unsigned short ushort16;

// fp32 -> bf16 with round-half-up (cheap: add 0x8000, take hi16)
static __device__ __forceinline__ ushort16 f2bf(float v) {
  uint32 u = __builtin_bit_cast(uint32, v);
  return (ushort16)((u + 0x8000u) >> 16);
}

// async 16B global->LDS (fire-and-forget; vmcnt-counted)
static __device__ __forceinline__ void gload_lds16(const float* g, float* l) {
  __builtin_amdgcn_global_load_lds(
      (const __attribute__((address_space(1))) void*)g,
      (__attribute__((address_space(3))) void*)l, 16, 0, 0);
}

// ---------------------------------------------------------------------------
// Kernel 1 (fused): blocks [0,MOMB) -> xyz moments; blocks [MOMB,MOMB+128) ->
// wb transpose to bf16.
// ---------------------------------------------------------------------------
#define MOMB 256
__global__ __launch_bounds__(256) void k_pre(const float* __restrict__ gx,
                                             const float* __restrict__ wb,
                                             float* __restrict__ ws) {
  if (blockIdx.x >= MOMB) {
    int idx = (int)(blockIdx.x - MOMB) * 256 + threadIdx.x;  // 0..32767
    int ci = idx >> 9;
    int col = idx & 511;
    ((ushort16*)(ws + WS_WBT))[col * 64 + ci] = f2bf(wb[idx]);
    return;
  }
  float s[14];
#pragma unroll
  for (int i = 0; i < 14; ++i) s[i] = 0.f;
  int tid = blockIdx.x * 256 + threadIdx.x;  // 0..65535
  const int nth = MOMB * 256;
  for (int p = tid; p < PTOT; p += nth) {
    int b = p >> 17;
    int r = p & (NKP - 1);
    const float* base = gx + (size_t)b * 3 * NKP + r;
    float v[4];
    v[0] = base[0];
    v[1] = base[NKP];
    v[2] = base[2 * NKP];
    v[3] = sqrtf(v[0] * v[0] + v[1] * v[1] + v[2] * v[2]);
#pragma unroll
    for (int j = 0; j < 4; ++j) s[j] += v[j];
    int idx = 4;
#pragma unroll
    for (int j = 0; j < 4; ++j)
#pragma unroll
      for (int l = j; l < 4; ++l) s[idx++] += v[j] * v[l];
  }
#pragma unroll
  for (int i = 0; i < 14; ++i) {
    float x = s[i];
#pragma unroll
    for (int off = 32; off > 0; off >>= 1) x += __shfl_down(x, off, 64);
    s[i] = x;
  }
  __shared__ float red[4][14];
  int wave = threadIdx.x >> 6;
  if ((threadIdx.x & 63) == 0) {
#pragma unroll
    for (int i = 0; i < 14; ++i) red[wave][i] = s[i];
  }
  __syncthreads();
  if (threadIdx.x < 14) {
    float v = red[0][threadIdx.x] + red[1][threadIdx.x] +
              red[2][threadIdx.x] + red[3][threadIdx.x];
    atomicAdd(&ws[WS_MOM + threadIdx.x * 16], v);
  }
}

// ---------------------------------------------------------------------------
// Kernel 2: main MFMA kernel — channel-split waves, FORCED-resident weights,
// post-MFMA scaling, 8-subtile double-buffered async pipeline with
// store-excluding counted vmcnt.
//
// vmcnt accounting (in-order retirement, all VMEM ops counted):
//   prologue: [fold loads][bw x16][gx x6][stage0 x4][stage1 x4][scorenet w2..]
//   E(0): vmcnt(4) lgkmcnt(0)       -> leaves stage1 in flight
//   steady E(s), s=1..6: newest 20 = stores(s-1) x16 + stage(s+1) x4
//                vmcnt(20)          -> waits exactly until stage(s) landed,
//                                      leaves prev stores + next stage in flight
//   E(7): vmcnt(16)                 -> newest 16 = stores(6)
// Every transition fenced with sched_barrier(0); stores live between two
// fences so the counts are exact. bw kept resident via opaque asm (+v) so
// the compiler can neither remat the loads nor sink VMEM into compute.
//  LDS = 2*16KB bufs + 16KB scores = 48KB -> 3 blocks/CU.
// ---------------------------------------------------------------------------
#define PPB 512   // points per block
#define SUB 64    // points per subtile
#define SM_SCL 8192  // float idx: scores SoA [m][512]

__global__ __launch_bounds__(256, 3) void k_main_mfma(
    const float* __restrict__ gx, const float* __restrict__ feat,
    const float* __restrict__ w1, const float* __restrict__ g1,
    const float* __restrict__ b1, const float* __restrict__ w2,
    const float* __restrict__ b2, const ushort16* __restrict__ wbt,
    float* __restrict__ ws, float* __restrict__ out) {
  __shared__ float smem[12288];  // 48 KB

  const int t = threadIdx.x;
  const int pblk = blockIdx.x * PPB;
  const int b = pblk >> 17;
  const int r0 = pblk & (NKP - 1);
  const int w = t >> 6;
  const int L = t & 63;
  const int l16 = L & 15;
  const int q4 = L >> 4;
  const int wchan = w * 16;

  // ---- inline BN1 fold (was k_finalize1) — FIRST, so its loads are oldest
  float a1r[HID], b1r[HID];
  {
    const float invP = 1.f / (float)PTOT;
    float mu[4], S[4][4];
#pragma unroll
    for (int j = 0; j < 4; ++j) mu[j] = ws[WS_MOM + j * 16] * invP;
    int idx = 4;
#pragma unroll
    for (int j = 0; j < 4; ++j)
#pragma unroll
      for (int l = j; l < 4; ++l) {
        float v = ws[WS_MOM + idx * 16] * invP;
        ++idx;
        S[j][l] = v;
        S[l][j] = v;
      }
#pragma unroll
    for (int c = 0; c < HID; ++c) {
      float wv[4];
#pragma unroll
      for (int j = 0; j < 4; ++j) wv[j] = w1[c * 4 + j];
      float mean = 0.f;
#pragma unroll
      for (int j = 0; j < 4; ++j) mean += wv[j] * mu[j];
      float Et2 = 0.f;
#pragma unroll
      for (int j = 0; j < 4; ++j)
#pragma unroll
        for (int l = 0; l < 4; ++l) Et2 += wv[j] * wv[l] * S[j][l];
      float var = Et2 - mean * mean;
      float a = g1[c] * rsqrtf(var + EPS);
      a1r[c] = a;
      b1r[c] = b1[c] - a * mean;
    }
  }

  // ---- resident weight fragments; opaque asm pins them (no remat, no sink)
  uint4v bwu[PM][2];
#pragma unroll
  for (int m = 0; m < PM; ++m)
#pragma unroll
    for (int ks = 0; ks < 2; ++ks)
      bwu[m][ks] = *(const uint4v*)(wbt + (m * 64 + wchan + l16) * 64 +
                                    ks * 32 + q4 * 8);
#pragma unroll
  for (int m = 0; m < PM; ++m)
    asm volatile("" : "+v"(bwu[m][0]), "+v"(bwu[m][1]));

  // ---- gx loads for scorenet
  float px[2], py[2], pz[2];
  {
    const float* gb = gx + (size_t)b * 3 * NKP + r0;
#pragma unroll
    for (int pp = 0; pp < 2; ++pp) {
      int p = t + pp * 256;
      px[pp] = gb[p];
      py[pp] = gb[NKP + p];
      pz[pp] = gb[2 * NKP + p];
    }
  }

  const float* fb = feat + (size_t)b * CIN * NKP + r0;
  // stage subtile s into buf[s&1]: 16 chunks x 1KB; wave issues 4.
  auto STAGE = [&](int s) {
    float* dst = &smem[(s & 1) * 4096];
    const float* src = fb + s * SUB;
#pragma unroll
    for (int i = 0; i < 4; ++i) {
      int chunk = w * 4 + i;
      int ci = chunk * 4 + q4;
      int sp = (l16 << 2) ^ (((ci >> 3) & 1) << 4);  // inv-swizzled src
      gload_lds16(src + (size_t)ci * NKP + sp, dst + chunk * 256);
    }
  };

  STAGE(0);
  STAGE(1);
  __builtin_amdgcn_sched_barrier(0);

  // ---- ScoreNet: all 256 threads, 2 points each -> scl SoA [m][512]
#pragma unroll
  for (int pp = 0; pp < 2; ++pp) {
    float x = px[pp], y = py[pp], z = pz[pp];
    float ed = sqrtf(x * x + y * y + z * z);
    float h[HID];
#pragma unroll
    for (int c = 0; c < HID; ++c) {
      float tv = w1[c * 4 + 0] * x + w1[c * 4 + 1] * y + w1[c * 4 + 2] * z +
                 w1[c * 4 + 3] * ed;
      h[c] = fmaxf(a1r[c] * tv + b1r[c], 0.f);
    }
    float sc[PM];
#pragma unroll
    for (int m = 0; m < PM; ++m) {
      float a = b2[m];
#pragma unroll
      for (int c = 0; c < HID; ++c) a += w2[m * HID + c] * h[c];
      sc[m] = a;
    }
    float mx = sc[0];
#pragma unroll
    for (int m = 1; m < PM; ++m) mx = fmaxf(mx, sc[m]);
    float esum = 0.f;
#pragma unroll
    for (int m = 0; m < PM; ++m) {
      sc[m] = __expf(sc[m] - mx);
      esum += sc[m];
    }
    float inv = 1.f / (1.f + esum);
    int p = t + pp * 256;
#pragma unroll
    for (int m = 0; m < PM; ++m) smem[SM_SCL + m * 512 + p] = sc[m] * inv;
  }

  float sacc[4] = {0.f, 0.f, 0.f, 0.f};
  float qacc[4] = {0.f, 0.f, 0.f, 0.f};
  float* ob = out + (size_t)b * COUT * NKP + r0;

  auto COMPUTE = [&](int s) {
    const float* bufp = &smem[(s & 1) * 4096];
    // pack feat fragments to bf16 once (unscaled)
    uint4v ffb[4][2];
#pragma unroll
    for (int rt = 0; rt < 4; ++rt) {
      int p = rt * 16 + l16;
#pragma unroll
      for (int ks = 0; ks < 2; ++ks) {
        int cib = ks * 32 + q4 * 8;
        int psw = p ^ (((cib >> 3) & 1) << 4);
        const float* cp = bufp + cib * 64 + psw;
#pragma unroll
        for (int e = 0; e < 4; ++e) {
          uint32 u0 = __builtin_bit_cast(uint32, cp[(2 * e) * 64]) + 0x8000u;
          uint32 u1 =
              __builtin_bit_cast(uint32, cp[(2 * e + 1) * 64]) + 0x8000u;
          ffb[rt][ks][e] = __builtin_amdgcn_perm(u1, u0, 0x07060302u);
        }
      }
    }
    float4v fin[4];
#pragma unroll
    for (int rt = 0; rt < 4; ++rt) fin[rt] = (float4v)0.f;
#pragma unroll
    for (int m = 0; m < PM; ++m) {
      float sm[4];
#pragma unroll
      for (int rt = 0; rt < 4; ++rt)
        sm[rt] = smem[SM_SCL + m * 512 + s * SUB + rt * 16 + l16];  // broadcast
#pragma unroll
      for (int rt = 0; rt < 4; ++rt) {
        float4v g = (float4v)0.f;
        g = __builtin_amdgcn_mfma_f32_16x16x32_bf16(
            __builtin_bit_cast(short8, bwu[m][0]),
            __builtin_bit_cast(short8, ffb[rt][0]), g, 0, 0, 0);
        g = __builtin_amdgcn_mfma_f32_16x16x32_bf16(
            __builtin_bit_cast(short8, bwu[m][1]),
            __builtin_bit_cast(short8, ffb[rt][1]), g, 0, 0, 0);
#pragma unroll
        for (int r = 0; r < 4; ++r) fin[rt][r] += sm[rt] * g[r];
      }
    }
    // stores: exactly 16 global_store_dword, fenced so the vmcnt counts hold
    __builtin_amdgcn_sched_barrier(0);
#pragma unroll
    for (int rt = 0; rt < 4; ++rt) {
      int p = s * SUB + rt * 16 + l16;
#pragma unroll
      for (int r = 0; r < 4; ++r) {
        float v = fin[rt][r];
        ob[(size_t)(wchan + q4 * 4 + r) * NKP + p] = v;
        sacc[r] += v;
        qacc[r] += v * v;
      }
    }
  };

#define ENTRY(VM_STR)                                       \
  asm volatile("s_waitcnt vmcnt(" VM_STR ")" ::: "memory"); \
  __builtin_amdgcn_s_barrier();                             \
  __builtin_amdgcn_sched_barrier(0);

#define EXITB()                      \
  __builtin_amdgcn_sched_barrier(0); \
  __builtin_amdgcn_s_barrier();      \
  __builtin_amdgcn_sched_barrier(0);

  // s = 0 (also drain scl ds_writes for all waves via lgkmcnt)
  asm volatile("s_waitcnt vmcnt(4) lgkmcnt(0)" ::: "memory");
  __builtin_amdgcn_s_barrier();
  __builtin_amdgcn_sched_barrier(0);
  COMPUTE(0);
  EXITB();
  STAGE(2);
  __builtin_amdgcn_sched_barrier(0);

  ENTRY("20") COMPUTE(1); EXITB(); STAGE(3); __builtin_amdgcn_sched_barrier(0);
  ENTRY("20") COMPUTE(2); EXITB(); STAGE(4); __builtin_amdgcn_sched_barrier(0);
  ENTRY("20") COMPUTE(3); EXITB(); STAGE(5); __builtin_amdgcn_sched_barrier(0);
  ENTRY("20") COMPUTE(4); EXITB(); STAGE(6); __builtin_amdgcn_sched_barrier(0);
  ENTRY("20") COMPUTE(5); EXITB(); STAGE(7); __builtin_amdgcn_sched_barrier(0);
  ENTRY("20") COMPUTE(6); EXITB();
  ENTRY("16") COMPUTE(7);

#undef ENTRY
#undef EXITB

  // ---- stats: reduce over the 16 l16-lanes of each q-group, then atomics.
#pragma unroll
  for (int off = 1; off < 16; off <<= 1) {
#pragma unroll
    for (int r = 0; r < 4; ++r) {
      sacc[r] += __shfl_xor(sacc[r], off, 64);
      qacc[r] += __shfl_xor(qacc[r], off, 64);
    }
  }
  if (l16 == 0) {
    int slot = blockIdx.x & 31;
#pragma unroll
    for (int r = 0; r < 4; ++r) {
      atomicAdd(&ws[WS_PSUM + slot * 64 + wchan + q4 * 4 + r], sacc[r]);
      atomicAdd(&ws[WS_PSQ + slot * 64 + wchan + q4 * 4 + r], qacc[r]);
    }
  }
}

// ---------------------------------------------------------------------------
// Kernel 3: in-place normalize + ReLU with inlined BN2 fold (was k_finalize2).
// Each block folds the 32 partial slots (8KB, L2-hot) into LDS, then streams.
// ---------------------------------------------------------------------------
#define NORMB 4096
__global__ __launch_bounds__(256) void k_norm(float* __restrict__ out,
                                              const float* __restrict__ ws,
                                              const float* __restrict__ g_out,
                                              const float* __restrict__ b_out) {
  __shared__ float a2s[COUT], b2s[COUT];
  const int t = threadIdx.x;
  if (t < COUT) {
    float s = 0.f, q = 0.f;
#pragma unroll
    for (int sl = 0; sl < 32; ++sl) {
      s += ws[WS_PSUM + sl * 64 + t];
      q += ws[WS_PSQ + sl * 64 + t];
    }
    const float invP = 1.f / (float)PTOT;
    float mean = s * invP;
    float var = q * invP - mean * mean;
    float a = g_out[t] * rsqrtf(var + EPS);
    a2s[t] = a;
    b2s[t] = b_out[t] - a * mean;
  }
  __syncthreads();
  size_t i4 = (size_t)blockIdx.x * 256 + t;
  const size_t stride = (size_t)NORMB * 256;
  float4* p = (float4*)out;
#pragma unroll
  for (int it = 0; it < 8; ++it, i4 += stride) {
    int c = (int)((i4 >> 15) & 63);  // elem = i4*4; c = (elem>>17)&63
    float a = a2s[c];
    float bb = b2s[c];
    float4 v = p[i4];
    v.x = fmaxf(a * v.x + bb, 0.f);
    v.y = fmaxf(a * v.y + bb, 0.f);
    v.z = fmaxf(a * v.z + bb, 0.f);
    v.w = fmaxf(a * v.w + bb, 0.f);
    p[i4] = v;
  }
}

extern "C" void kernel_launch(void* const* d_in, const int* in_sizes, int n_in,
                              void* d_out, int out_size, void* d_ws,
                              size_t ws_size, hipStream_t stream) {
  const float* gx = (const float*)d_in[0];
  const float* feat = (const float*)d_in[1];
  const float* w1 = (const float*)d_in[2];
  const float* g1 = (const float*)d_in[3];
  const float* b1 = (const float*)d_in[4];
  const float* w2 = (const float*)d_in[5];
  const float* b2 = (const float*)d_in[6];
  const float* wb = (const float*)d_in[7];
  const float* g_out = (const float*)d_in[8];
  const float* b_out = (const float*)d_in[9];
  float* out = (float*)d_out;
  float* ws = (float*)d_ws;
  ushort16* wbt = (ushort16*)(ws + WS_WBT);

  (void)in_sizes; (void)n_in; (void)out_size; (void)ws_size;

  hipMemsetAsync(d_ws, 0, WS_ZERO_FLOATS * sizeof(float), stream);

  k_pre<<<MOMB + 128, 256, 0, stream>>>(gx, wb, ws);
  k_main_mfma<<<PTOT / PPB, 256, 0, stream>>>(gx, feat, w1, g1, b1, w2, b2,
                                              wbt, ws, out);
  k_norm<<<NORMB, 256, 0, stream>>>(out, ws, g_out, b_out);
}

// Round 4
// 341.071 us; speedup vs baseline: 1.3059x; 1.0173x over previous
//
#include <hip/hip_runtime.h>
#include <hip/hip_bf16.h>
#include <math.h>

// Problem constants: B=4, N=4096, k=32, Cin=64, Cout=64, M=8, hidden=16
#define PB 4
#define PN 4096
#define PK 32
#define NKP (PN * PK)              // 131072 points per batch (2^17)
#define PTOT (PB * NKP)            // 524288 total points
#define CIN 64
#define COUT 64
#define PM 8
#define HID 16
#define EPS 1e-5f

// ws float layout
#define WS_MOM 0            // 14 slots x stride 16 floats = [0..224)
#define WS_PSUM 416         // 32 slots x 64: out channel sum partials
#define WS_PSQ 2464         // 32 slots x 64: out channel sumsq partials
#define WS_ZERO_FLOATS 4512
#define WS_WBT 4608         // bf16 wbT[512][64] as ushort (32768 entries, 64 KB)

typedef __attribute__((ext_vector_type(8))) short short8;
typedef __attribute__((ext_vector_type(4))) float float4v;
typedef __attribute__((ext_vector_type(4))) unsigned int uint4v;
typedef unsigned int uint32;
typedef unsigned short ushort16;

// fp32 -> bf16 with round-half-up (cheap: add 0x8000, take hi16)
static __device__ __forceinline__ ushort16 f2bf(float v) {
  uint32 u = __builtin_bit_cast(uint32, v);
  return (ushort16)((u + 0x8000u) >> 16);
}

// async 16B global->LDS (fire-and-forget; vmcnt-counted)
static __device__ __forceinline__ void gload_lds16(const float* g, float* l) {
  __builtin_amdgcn_global_load_lds(
      (const __attribute__((address_space(1))) void*)g,
      (__attribute__((address_space(3))) void*)l, 16, 0, 0);
}

// score LDS addressing: [p][8] floats, XOR-swizzled so the 4 q4-groups of a
// read instr land on distinct bank octets. addr(p) = p*8 ^ (((p>>2)&3)<<3).
static __device__ __forceinline__ int scl_addr(int p) {
  return (p * 8) ^ (((p >> 2) & 3) << 3);
}

// ---------------------------------------------------------------------------
// Kernel 1 (fused): blocks [0,MOMB) -> xyz moments (dwordx4 vectorized);
// blocks [MOMB,MOMB+128) -> wb transpose to bf16.
// ---------------------------------------------------------------------------
#define MOMB 256
__global__ __launch_bounds__(256) void k_pre(const float* __restrict__ gx,
                                             const float* __restrict__ wb,
                                             float* __restrict__ ws) {
  if (blockIdx.x >= MOMB) {
    int idx = (int)(blockIdx.x - MOMB) * 256 + threadIdx.x;  // 0..32767
    int ci = idx >> 9;
    int col = idx & 511;
    ((ushort16*)(ws + WS_WBT))[col * 64 + ci] = f2bf(wb[idx]);
    return;
  }
  float s[14];
#pragma unroll
  for (int i = 0; i < 14; ++i) s[i] = 0.f;
  int tid = blockIdx.x * 256 + threadIdx.x;  // 0..65535
  const int nth = MOMB * 256;
  for (int p4 = tid * 4; p4 < PTOT; p4 += nth * 4) {
    int b = p4 >> 17;
    int r = p4 & (NKP - 1);
    const float* base = gx + (size_t)b * 3 * NKP + r;
    float4v xv = *(const float4v*)(base);
    float4v yv = *(const float4v*)(base + NKP);
    float4v zv = *(const float4v*)(base + 2 * NKP);
#pragma unroll
    for (int j = 0; j < 4; ++j) {
      float v[4];
      v[0] = xv[j];
      v[1] = yv[j];
      v[2] = zv[j];
      v[3] = sqrtf(v[0] * v[0] + v[1] * v[1] + v[2] * v[2]);
#pragma unroll
      for (int q = 0; q < 4; ++q) s[q] += v[q];
      int idx = 4;
#pragma unroll
      for (int q = 0; q < 4; ++q)
#pragma unroll
        for (int l = q; l < 4; ++l) s[idx++] += v[q] * v[l];
    }
  }
#pragma unroll
  for (int i = 0; i < 14; ++i) {
    float x = s[i];
#pragma unroll
    for (int off = 32; off > 0; off >>= 1) x += __shfl_down(x, off, 64);
    s[i] = x;
  }
  __shared__ float red[4][14];
  int wave = threadIdx.x >> 6;
  if ((threadIdx.x & 63) == 0) {
#pragma unroll
    for (int i = 0; i < 14; ++i) red[wave][i] = s[i];
  }
  __syncthreads();
  if (threadIdx.x < 14) {
    float v = red[0][threadIdx.x] + red[1][threadIdx.x] +
              red[2][threadIdx.x] + red[3][threadIdx.x];
    atomicAdd(&ws[WS_MOM + threadIdx.x * 16], v);
  }
}

// ---------------------------------------------------------------------------
// Kernel 2: main MFMA kernel — round-0 operand order (A=feat, B=wb) so the
// D-tile is point-major: lane (q4,l16) reg r holds out[c=wchan+l16][p=..+q4*4+r]
// -> accumulator IS a float4 along p -> direct global_store_dwordx4 (1KB/instr,
// 16 full cache lines). This attacks the measured ~1.15 TB/s VMEM-instruction
// ceiling (4B-lane stores) seen in rounds 0-3.
//  - channel-split waves, resident bw (asm-pinned), post-MFMA scaling
//  - scores in [p][8] XOR-swizzled AoS -> per-r b128 broadcast reads
//  - 8-subtile dbuf async pipeline; steady vmcnt(8)=stores(s)x4+stage(s+2)x4
//  LDS = 2*16KB feat + 16KB scl = 48KB -> 3 blocks/CU.
// ---------------------------------------------------------------------------
#define PPB 512   // points per block
#define SUB 64    // points per subtile
#define SM_SCL 8192  // float idx

__global__ __launch_bounds__(256, 3) void k_main_mfma(
    const float* __restrict__ gx, const float* __restrict__ feat,
    const float* __restrict__ w1, const float* __restrict__ g1,
    const float* __restrict__ b1, const float* __restrict__ w2,
    const float* __restrict__ b2, const ushort16* __restrict__ wbt,
    float* __restrict__ ws, float* __restrict__ out) {
  __shared__ float smem[12288];  // 48 KB

  const int t = threadIdx.x;
  const int pblk = blockIdx.x * PPB;
  const int b = pblk >> 17;
  const int r0 = pblk & (NKP - 1);
  const int w = t >> 6;
  const int L = t & 63;
  const int l16 = L & 15;
  const int q4 = L >> 4;
  const int wchan = w * 16;

  // ---- inline BN1 fold — FIRST, so its loads are oldest
  float a1r[HID], b1r[HID];
  {
    const float invP = 1.f / (float)PTOT;
    float mu[4], S[4][4];
#pragma unroll
    for (int j = 0; j < 4; ++j) mu[j] = ws[WS_MOM + j * 16] * invP;
    int idx = 4;
#pragma unroll
    for (int j = 0; j < 4; ++j)
#pragma unroll
      for (int l = j; l < 4; ++l) {
        float v = ws[WS_MOM + idx * 16] * invP;
        ++idx;
        S[j][l] = v;
        S[l][j] = v;
      }
#pragma unroll
    for (int c = 0; c < HID; ++c) {
      float wv[4];
#pragma unroll
      for (int j = 0; j < 4; ++j) wv[j] = w1[c * 4 + j];
      float mean = 0.f;
#pragma unroll
      for (int j = 0; j < 4; ++j) mean += wv[j] * mu[j];
      float Et2 = 0.f;
#pragma unroll
      for (int j = 0; j < 4; ++j)
#pragma unroll
        for (int l = 0; l < 4; ++l) Et2 += wv[j] * wv[l] * S[j][l];
      float var = Et2 - mean * mean;
      float a = g1[c] * rsqrtf(var + EPS);
      a1r[c] = a;
      b1r[c] = b1[c] - a * mean;
    }
  }

  // ---- resident weight fragments; opaque asm pins them (no remat, no sink)
  uint4v bwu[PM][2];
#pragma unroll
  for (int m = 0; m < PM; ++m)
#pragma unroll
    for (int ks = 0; ks < 2; ++ks)
      bwu[m][ks] = *(const uint4v*)(wbt + (m * 64 + wchan + l16) * 64 +
                                    ks * 32 + q4 * 8);
#pragma unroll
  for (int m = 0; m < PM; ++m)
    asm volatile("" : "+v"(bwu[m][0]), "+v"(bwu[m][1]));

  // ---- gx loads for scorenet
  float px[2], py[2], pz[2];
  {
    const float* gb = gx + (size_t)b * 3 * NKP + r0;
#pragma unroll
    for (int pp = 0; pp < 2; ++pp) {
      int p = t + pp * 256;
      px[pp] = gb[p];
      py[pp] = gb[NKP + p];
      pz[pp] = gb[2 * NKP + p];
    }
  }

  const float* fb = feat + (size_t)b * CIN * NKP + r0;
  // stage subtile s into buf[s&1]: 16 chunks x 1KB; wave issues 4.
  auto STAGE = [&](int s) {
    float* dst = &smem[(s & 1) * 4096];
    const float* src = fb + s * SUB;
#pragma unroll
    for (int i = 0; i < 4; ++i) {
      int chunk = w * 4 + i;
      int ci = chunk * 4 + q4;
      int sp = (l16 << 2) ^ (((ci >> 3) & 1) << 4);  // inv-swizzled src
      gload_lds16(src + (size_t)ci * NKP + sp, dst + chunk * 256);
    }
  };

  STAGE(0);
  STAGE(1);
  __builtin_amdgcn_sched_barrier(0);

  // ---- ScoreNet: 2 points/thread -> scl AoS [p][8] (swizzled), float4 writes
#pragma unroll
  for (int pp = 0; pp < 2; ++pp) {
    float x = px[pp], y = py[pp], z = pz[pp];
    float ed = sqrtf(x * x + y * y + z * z);
    float h[HID];
#pragma unroll
    for (int c = 0; c < HID; ++c) {
      float tv = w1[c * 4 + 0] * x + w1[c * 4 + 1] * y + w1[c * 4 + 2] * z +
                 w1[c * 4 + 3] * ed;
      h[c] = fmaxf(a1r[c] * tv + b1r[c], 0.f);
    }
    float sc[PM];
#pragma unroll
    for (int m = 0; m < PM; ++m) {
      float a = b2[m];
#pragma unroll
      for (int c = 0; c < HID; ++c) a += w2[m * HID + c] * h[c];
      sc[m] = a;
    }
    float mx = sc[0];
#pragma unroll
    for (int m = 1; m < PM; ++m) mx = fmaxf(mx, sc[m]);
    float esum = 0.f;
#pragma unroll
    for (int m = 0; m < PM; ++m) {
      sc[m] = __expf(sc[m] - mx);
      esum += sc[m];
    }
    float inv = 1.f / (1.f + esum);
    int p = t + pp * 256;
    int sa = scl_addr(p);
    float4v v0, v1;
#pragma unroll
    for (int m = 0; m < 4; ++m) v0[m] = sc[m] * inv;
#pragma unroll
    for (int m = 0; m < 4; ++m) v1[m] = sc[4 + m] * inv;
    *(float4v*)&smem[SM_SCL + sa] = v0;
    *(float4v*)&smem[SM_SCL + sa + 4] = v1;
  }

  float sacc = 0.f, qacc = 0.f;
  // lane's output row: channel = wchan + l16, points r0 + s*64 + rt*16 + q4*4
  float* obl = out + (size_t)b * COUT * NKP + (size_t)(wchan + l16) * NKP + r0 +
               q4 * 4;

  auto COMPUTE = [&](int s) {
    const float* bufp = &smem[(s & 1) * 4096];
#pragma unroll
    for (int rt = 0; rt < 4; ++rt) {
      // pack A fragment (feat rows p = rt*16 + l16) to bf16, unscaled
      uint4v ffb[2];
#pragma unroll
      for (int ks = 0; ks < 2; ++ks) {
        int cib = ks * 32 + q4 * 8;
        int psw = (rt * 16 + l16) ^ (((cib >> 3) & 1) << 4);
        const float* cp = bufp + cib * 64 + psw;
#pragma unroll
        for (int e = 0; e < 4; ++e) {
          uint32 u0 = __builtin_bit_cast(uint32, cp[(2 * e) * 64]) + 0x8000u;
          uint32 u1 =
              __builtin_bit_cast(uint32, cp[(2 * e + 1) * 64]) + 0x8000u;
          ffb[ks][e] = __builtin_amdgcn_perm(u1, u0, 0x07060302u);
        }
      }
      // 8 independent MFMA chains: g[m] = W_m . f  (D: row=p, col=c)
      float4v g[PM];
#pragma unroll
      for (int m = 0; m < PM; ++m) {
        float4v z = (float4v)0.f;
        z = __builtin_amdgcn_mfma_f32_16x16x32_bf16(
            __builtin_bit_cast(short8, ffb[0]),
            __builtin_bit_cast(short8, bwu[m][0]), z, 0, 0, 0);
        g[m] = __builtin_amdgcn_mfma_f32_16x16x32_bf16(
            __builtin_bit_cast(short8, ffb[1]),
            __builtin_bit_cast(short8, bwu[m][1]), z, 0, 0, 0);
      }
      // post-MFMA scale: fin[r] = sum_m scl[p+r][m] * g[m][r]
      float4v fin;
#pragma unroll
      for (int r = 0; r < 4; ++r) {
        int pr = s * SUB + rt * 16 + q4 * 4 + r;
        int sa = scl_addr(pr);
        float4v s0 = *(const float4v*)&smem[SM_SCL + sa];
        float4v s1 = *(const float4v*)&smem[SM_SCL + sa + 4];
        float a = 0.f;
#pragma unroll
        for (int m = 0; m < 4; ++m) a += s0[m] * g[m][r];
#pragma unroll
        for (int m = 0; m < 4; ++m) a += s1[m] * g[4 + m][r];
        fin[r] = a;
        sacc += a;
        qacc += a * a;
      }
      // ONE dwordx4 store per rt: 64 lanes x 16B = 1KB, 16 full 64B lines
      __builtin_amdgcn_sched_barrier(0);
      *(float4v*)(obl + s * SUB + rt * 16) = fin;
      __builtin_amdgcn_sched_barrier(0);
    }
  };

#define ENTRY(VM_STR)                                       \
  asm volatile("s_waitcnt vmcnt(" VM_STR ")" ::: "memory"); \
  __builtin_amdgcn_s_barrier();                             \
  __builtin_amdgcn_sched_barrier(0);

#define EXITB()                      \
  __builtin_amdgcn_sched_barrier(0); \
  __builtin_amdgcn_s_barrier();      \
  __builtin_amdgcn_sched_barrier(0);

  // s = 0 (also drain scl ds_writes for all waves via lgkmcnt)
  asm volatile("s_waitcnt vmcnt(4) lgkmcnt(0)" ::: "memory");
  __builtin_amdgcn_s_barrier();
  __builtin_amdgcn_sched_barrier(0);
  COMPUTE(0);
  EXITB();
  STAGE(2);
  __builtin_amdgcn_sched_barrier(0);

  ENTRY("8") COMPUTE(1); EXITB(); STAGE(3); __builtin_amdgcn_sched_barrier(0);
  ENTRY("8") COMPUTE(2); EXITB(); STAGE(4); __builtin_amdgcn_sched_barrier(0);
  ENTRY("8") COMPUTE(3); EXITB(); STAGE(5); __builtin_amdgcn_sched_barrier(0);
  ENTRY("8") COMPUTE(4); EXITB(); STAGE(6); __builtin_amdgcn_sched_barrier(0);
  ENTRY("8") COMPUTE(5); EXITB(); STAGE(7); __builtin_amdgcn_sched_barrier(0);
  ENTRY("8") COMPUTE(6); EXITB();
  ENTRY("4") COMPUTE(7);

#undef ENTRY
#undef EXITB

  // ---- stats: lane owns channel wchan+l16; reduce over q4 groups (p).
  sacc += __shfl_xor(sacc, 16, 64);
  qacc += __shfl_xor(qacc, 16, 64);
  sacc += __shfl_xor(sacc, 32, 64);
  qacc += __shfl_xor(qacc, 32, 64);
  if (L < 16) {
    int slot = blockIdx.x & 31;
    atomicAdd(&ws[WS_PSUM + slot * 64 + wchan + l16], sacc);
    atomicAdd(&ws[WS_PSQ + slot * 64 + wchan + l16], qacc);
  }
}

// ---------------------------------------------------------------------------
// Kernel 3: in-place normalize + ReLU with inlined BN2 fold.
// ---------------------------------------------------------------------------
#define NORMB 4096
__global__ __launch_bounds__(256) void k_norm(float* __restrict__ out,
                                              const float* __restrict__ ws,
                                              const float* __restrict__ g_out,
                                              const float* __restrict__ b_out) {
  __shared__ float a2s[COUT], b2s[COUT];
  const int t = threadIdx.x;
  if (t < COUT) {
    float s = 0.f, q = 0.f;
#pragma unroll
    for (int sl = 0; sl < 32; ++sl) {
      s += ws[WS_PSUM + sl * 64 + t];
      q += ws[WS_PSQ + sl * 64 + t];
    }
    const float invP = 1.f / (float)PTOT;
    float mean = s * invP;
    float var = q * invP - mean * mean;
    float a = g_out[t] * rsqrtf(var + EPS);
    a2s[t] = a;
    b2s[t] = b_out[t] - a * mean;
  }
  __syncthreads();
  size_t i4 = (size_t)blockIdx.x * 256 + t;
  const size_t stride = (size_t)NORMB * 256;
  float4* p = (float4*)out;
#pragma unroll
  for (int it = 0; it < 8; ++it, i4 += stride) {
    int c = (int)((i4 >> 15) & 63);  // elem = i4*4; c = (elem>>17)&63
    float a = a2s[c];
    float bb = b2s[c];
    float4 v = p[i4];
    v.x = fmaxf(a * v.x + bb, 0.f);
    v.y = fmaxf(a * v.y + bb, 0.f);
    v.z = fmaxf(a * v.z + bb, 0.f);
    v.w = fmaxf(a * v.w + bb, 0.f);
    p[i4] = v;
  }
}

extern "C" void kernel_launch(void* const* d_in, const int* in_sizes, int n_in,
                              void* d_out, int out_size, void* d_ws,
                              size_t ws_size, hipStream_t stream) {
  const float* gx = (const float*)d_in[0];
  const float* feat = (const float*)d_in[1];
  const float* w1 = (const float*)d_in[2];
  const float* g1 = (const float*)d_in[3];
  const float* b1 = (const float*)d_in[4];
  const float* w2 = (const float*)d_in[5];
  const float* b2 = (const float*)d_in[6];
  const float* wb = (const float*)d_in[7];
  const float* g_out = (const float*)d_in[8];
  const float* b_out = (const float*)d_in[9];
  float* out = (float*)d_out;
  float* ws = (float*)d_ws;
  ushort16* wbt = (ushort16*)(ws + WS_WBT);

  (void)in_sizes; (void)n_in; (void)out_size; (void)ws_size;

  hipMemsetAsync(d_ws, 0, WS_ZERO_FLOATS * sizeof(float), stream);

  k_pre<<<MOMB + 128, 256, 0, stream>>>(gx, wb, ws);
  k_main_mfma<<<PTOT / PPB, 256, 0, stream>>>(gx, feat, w1, g1, b1, w2, b2,
                                              wbt, ws, out);
  k_norm<<<NORMB, 256, 0, stream>>>(out, ws, g_out, b_out);
}

// Round 6
// 337.202 us; speedup vs baseline: 1.3209x; 1.0115x over previous
//
#include <hip/hip_runtime.h>
#include <hip/hip_bf16.h>
#include <math.h>

// Problem constants: B=4, N=4096, k=32, Cin=64, Cout=64, M=8, hidden=16
#define PB 4
#define PN 4096
#define PK 32
#define NKP (PN * PK)              // 131072 points per batch (2^17)
#define PTOT (PB * NKP)            // 524288 total points
#define CIN 64
#define COUT 64
#define PM 8
#define HID 16
#define EPS 1e-5f

// ws float layout
#define WS_MOM 0            // 14 slots x stride 16 floats = [0..224)
#define WS_PSUM 416         // 32 slots x 64: out channel sum partials
#define WS_PSQ 2464         // 32 slots x 64: out channel sumsq partials
#define WS_ZERO_FLOATS 4512
#define WS_WBT 4608         // bf16 wbT[512][64] as ushort (32768 entries, 64 KB)

typedef __attribute__((ext_vector_type(8))) short short8;
typedef __attribute__((ext_vector_type(4))) float float4v;
typedef __attribute__((ext_vector_type(4))) unsigned int uint4v;
typedef unsigned int uint32;
typedef unsigned short ushort16;

// fp32 -> bf16 with round-half-up (cheap: add 0x8000, take hi16)
static __device__ __forceinline__ ushort16 f2bf(float v) {
  uint32 u = __builtin_bit_cast(uint32, v);
  return (ushort16)((u + 0x8000u) >> 16);
}

// async 16B global->LDS (fire-and-forget; vmcnt-counted)
static __device__ __forceinline__ void gload_lds16(const float* g, float* l) {
  __builtin_amdgcn_global_load_lds(
      (const __attribute__((address_space(1))) void*)g,
      (__attribute__((address_space(3))) void*)l, 16, 0, 0);
}

// score LDS addressing: [p][8] floats, XOR-swizzled so the 4 q4-groups of a
// read instr land on distinct bank octets. addr(p) = p*8 ^ (((p>>2)&3)<<3).
static __device__ __forceinline__ int scl_addr(int p) {
  return (p * 8) ^ (((p >> 2) & 3) << 3);
}

// ---------------------------------------------------------------------------
// Kernel 1 (fused): blocks [0,MOMB) -> xyz moments (dwordx4 vectorized);
// blocks [MOMB,MOMB+128) -> wb transpose to bf16.
// ---------------------------------------------------------------------------
#define MOMB 256
__global__ __launch_bounds__(256) void k_pre(const float* __restrict__ gx,
                                             const float* __restrict__ wb,
                                             float* __restrict__ ws) {
  if (blockIdx.x >= MOMB) {
    int idx = (int)(blockIdx.x - MOMB) * 256 + threadIdx.x;  // 0..32767
    int ci = idx >> 9;
    int col = idx & 511;
    ((ushort16*)(ws + WS_WBT))[col * 64 + ci] = f2bf(wb[idx]);
    return;
  }
  float s[14];
#pragma unroll
  for (int i = 0; i < 14; ++i) s[i] = 0.f;
  int tid = blockIdx.x * 256 + threadIdx.x;  // 0..65535
  const int nth = MOMB * 256;
  for (int p4 = tid * 4; p4 < PTOT; p4 += nth * 4) {
    int b = p4 >> 17;
    int r = p4 & (NKP - 1);
    const float* base = gx + (size_t)b * 3 * NKP + r;
    float4v xv = *(const float4v*)(base);
    float4v yv = *(const float4v*)(base + NKP);
    float4v zv = *(const float4v*)(base + 2 * NKP);
#pragma unroll
    for (int j = 0; j < 4; ++j) {
      float v[4];
      v[0] = xv[j];
      v[1] = yv[j];
      v[2] = zv[j];
      v[3] = sqrtf(v[0] * v[0] + v[1] * v[1] + v[2] * v[2]);
#pragma unroll
      for (int q = 0; q < 4; ++q) s[q] += v[q];
      int idx = 4;
#pragma unroll
      for (int q = 0; q < 4; ++q)
#pragma unroll
        for (int l = q; l < 4; ++l) s[idx++] += v[q] * v[l];
    }
  }
#pragma unroll
  for (int i = 0; i < 14; ++i) {
    float x = s[i];
#pragma unroll
    for (int off = 32; off > 0; off >>= 1) x += __shfl_down(x, off, 64);
    s[i] = x;
  }
  __shared__ float red[4][14];
  int wave = threadIdx.x >> 6;
  if ((threadIdx.x & 63) == 0) {
#pragma unroll
    for (int i = 0; i < 14; ++i) red[wave][i] = s[i];
  }
  __syncthreads();
  if (threadIdx.x < 14) {
    float v = red[0][threadIdx.x] + red[1][threadIdx.x] +
              red[2][threadIdx.x] + red[3][threadIdx.x];
    atomicAdd(&ws[WS_MOM + threadIdx.x * 16], v);
  }
}

// ---------------------------------------------------------------------------
// Kernel 2: main MFMA kernel — identical structure to round 4, but with the
// register allocator FORCED to the LDS-dictated occupancy:
//   amdgpu_waves_per_eu(3,3) -> VGPR budget ~168/wave.
// Round 2-4 post-mortem: the allocator targeted 6 waves/EU (VGPR_Count=84)
// on its own heuristic, spilling the 64-VGPR resident weight array to
// scratch. That injected scratch buffer-loads into the "VMEM-free" compute
// phase, mis-calibrated every counted vmcnt wait (scratch ops count in
// vmcnt), and added ~25MB of scratch write traffic — while LDS (48KB -> 3
// blocks/CU = 3 waves/EU) capped occupancy at 3 anyway, so the 84-reg
// target bought nothing. This attribute makes the r2-r4 design actually
// exist in hardware for the first time.
// ---------------------------------------------------------------------------
#define PPB 512   // points per block
#define SUB 64    // points per subtile
#define SM_SCL 8192  // float idx

__global__ __attribute__((amdgpu_flat_work_group_size(256, 256),
                          amdgpu_waves_per_eu(3, 3))) void k_main_mfma(
    const float* __restrict__ gx, const float* __restrict__ feat,
    const float* __restrict__ w1, const float* __restrict__ g1,
    const float* __restrict__ b1, const float* __restrict__ w2,
    const float* __restrict__ b2, const ushort16* __restrict__ wbt,
    float* __restrict__ ws, float* __restrict__ out) {
  __shared__ float smem[12288];  // 48 KB

  const int t = threadIdx.x;
  const int pblk = blockIdx.x * PPB;
  const int b = pblk >> 17;
  const int r0 = pblk & (NKP - 1);
  const int w = t >> 6;
  const int L = t & 63;
  const int l16 = L & 15;
  const int q4 = L >> 4;
  const int wchan = w * 16;

  // ---- inline BN1 fold — FIRST, so its loads are oldest
  float a1r[HID], b1r[HID];
  {
    const float invP = 1.f / (float)PTOT;
    float mu[4], S[4][4];
#pragma unroll
    for (int j = 0; j < 4; ++j) mu[j] = ws[WS_MOM + j * 16] * invP;
    int idx = 4;
#pragma unroll
    for (int j = 0; j < 4; ++j)
#pragma unroll
      for (int l = j; l < 4; ++l) {
        float v = ws[WS_MOM + idx * 16] * invP;
        ++idx;
        S[j][l] = v;
        S[l][j] = v;
      }
#pragma unroll
    for (int c = 0; c < HID; ++c) {
      float wv[4];
#pragma unroll
      for (int j = 0; j < 4; ++j) wv[j] = w1[c * 4 + j];
      float mean = 0.f;
#pragma unroll
      for (int j = 0; j < 4; ++j) mean += wv[j] * mu[j];
      float Et2 = 0.f;
#pragma unroll
      for (int j = 0; j < 4; ++j)
#pragma unroll
        for (int l = 0; l < 4; ++l) Et2 += wv[j] * wv[l] * S[j][l];
      float var = Et2 - mean * mean;
      float a = g1[c] * rsqrtf(var + EPS);
      a1r[c] = a;
      b1r[c] = b1[c] - a * mean;
    }
  }

  // ---- resident weight fragments; opaque asm pins them (no remat, no sink)
  uint4v bwu[PM][2];
#pragma unroll
  for (int m = 0; m < PM; ++m)
#pragma unroll
    for (int ks = 0; ks < 2; ++ks)
      bwu[m][ks] = *(const uint4v*)(wbt + (m * 64 + wchan + l16) * 64 +
                                    ks * 32 + q4 * 8);
#pragma unroll
  for (int m = 0; m < PM; ++m)
    asm volatile("" : "+v"(bwu[m][0]), "+v"(bwu[m][1]));

  // ---- gx loads for scorenet
  float px[2], py[2], pz[2];
  {
    const float* gb = gx + (size_t)b * 3 * NKP + r0;
#pragma unroll
    for (int pp = 0; pp < 2; ++pp) {
      int p = t + pp * 256;
      px[pp] = gb[p];
      py[pp] = gb[NKP + p];
      pz[pp] = gb[2 * NKP + p];
    }
  }

  const float* fb = feat + (size_t)b * CIN * NKP + r0;
  // stage subtile s into buf[s&1]: 16 chunks x 1KB; wave issues 4.
  auto STAGE = [&](int s) {
    float* dst = &smem[(s & 1) * 4096];
    const float* src = fb + s * SUB;
#pragma unroll
    for (int i = 0; i < 4; ++i) {
      int chunk = w * 4 + i;
      int ci = chunk * 4 + q4;
      int sp = (l16 << 2) ^ (((ci >> 3) & 1) << 4);  // inv-swizzled src
      gload_lds16(src + (size_t)ci * NKP + sp, dst + chunk * 256);
    }
  };

  STAGE(0);
  STAGE(1);
  __builtin_amdgcn_sched_barrier(0);

  // ---- ScoreNet: 2 points/thread -> scl AoS [p][8] (swizzled), float4 writes
#pragma unroll
  for (int pp = 0; pp < 2; ++pp) {
    float x = px[pp], y = py[pp], z = pz[pp];
    float ed = sqrtf(x * x + y * y + z * z);
    float h[HID];
#pragma unroll
    for (int c = 0; c < HID; ++c) {
      float tv = w1[c * 4 + 0] * x + w1[c * 4 + 1] * y + w1[c * 4 + 2] * z +
                 w1[c * 4 + 3] * ed;
      h[c] = fmaxf(a1r[c] * tv + b1r[c], 0.f);
    }
    float sc[PM];
#pragma unroll
    for (int m = 0; m < PM; ++m) {
      float a = b2[m];
#pragma unroll
      for (int c = 0; c < HID; ++c) a += w2[m * HID + c] * h[c];
      sc[m] = a;
    }
    float mx = sc[0];
#pragma unroll
    for (int m = 1; m < PM; ++m) mx = fmaxf(mx, sc[m]);
    float esum = 0.f;
#pragma unroll
    for (int m = 0; m < PM; ++m) {
      sc[m] = __expf(sc[m] - mx);
      esum += sc[m];
    }
    float inv = 1.f / (1.f + esum);
    int p = t + pp * 256;
    int sa = scl_addr(p);
    float4v v0, v1;
#pragma unroll
    for (int m = 0; m < 4; ++m) v0[m] = sc[m] * inv;
#pragma unroll
    for (int m = 0; m < 4; ++m) v1[m] = sc[4 + m] * inv;
    *(float4v*)&smem[SM_SCL + sa] = v0;
    *(float4v*)&smem[SM_SCL + sa + 4] = v1;
  }

  float sacc = 0.f, qacc = 0.f;
  // lane's output row: channel = wchan + l16, points r0 + s*64 + rt*16 + q4*4
  float* obl = out + (size_t)b * COUT * NKP + (size_t)(wchan + l16) * NKP + r0 +
               q4 * 4;

  auto COMPUTE = [&](int s) {
    const float* bufp = &smem[(s & 1) * 4096];
#pragma unroll
    for (int rt = 0; rt < 4; ++rt) {
      // pack A fragment (feat rows p = rt*16 + l16) to bf16, unscaled
      uint4v ffb[2];
#pragma unroll
      for (int ks = 0; ks < 2; ++ks) {
        int cib = ks * 32 + q4 * 8;
        int psw = (rt * 16 + l16) ^ (((cib >> 3) & 1) << 4);
        const float* cp = bufp + cib * 64 + psw;
#pragma unroll
        for (int e = 0; e < 4; ++e) {
          uint32 u0 = __builtin_bit_cast(uint32, cp[(2 * e) * 64]) + 0x8000u;
          uint32 u1 =
              __builtin_bit_cast(uint32, cp[(2 * e + 1) * 64]) + 0x8000u;
          ffb[ks][e] = __builtin_amdgcn_perm(u1, u0, 0x07060302u);
        }
      }
      // 8 independent MFMA chains: g[m] = W_m . f  (D: row=p, col=c)
      float4v g[PM];
#pragma unroll
      for (int m = 0; m < PM; ++m) {
        float4v z = (float4v)0.f;
        z = __builtin_amdgcn_mfma_f32_16x16x32_bf16(
            __builtin_bit_cast(short8, ffb[0]),
            __builtin_bit_cast(short8, bwu[m][0]), z, 0, 0, 0);
        g[m] = __builtin_amdgcn_mfma_f32_16x16x32_bf16(
            __builtin_bit_cast(short8, ffb[1]),
            __builtin_bit_cast(short8, bwu[m][1]), z, 0, 0, 0);
      }
      // post-MFMA scale: fin[r] = sum_m scl[p+r][m] * g[m][r]
      float4v fin;
#pragma unroll
      for (int r = 0; r < 4; ++r) {
        int pr = s * SUB + rt * 16 + q4 * 4 + r;
        int sa = scl_addr(pr);
        float4v s0 = *(const float4v*)&smem[SM_SCL + sa];
        float4v s1 = *(const float4v*)&smem[SM_SCL + sa + 4];
        float a = 0.f;
#pragma unroll
        for (int m = 0; m < 4; ++m) a += s0[m] * g[m][r];
#pragma unroll
        for (int m = 0; m < 4; ++m) a += s1[m] * g[4 + m][r];
        fin[r] = a;
        sacc += a;
        qacc += a * a;
      }
      // ONE dwordx4 store per rt: 64 lanes x 16B = 1KB, 16 full 64B lines
      __builtin_amdgcn_sched_barrier(0);
      *(float4v*)(obl + s * SUB + rt * 16) = fin;
      __builtin_amdgcn_sched_barrier(0);
    }
  };

#define ENTRY(VM_STR)                                       \
  asm volatile("s_waitcnt vmcnt(" VM_STR ")" ::: "memory"); \
  __builtin_amdgcn_s_barrier();                             \
  __builtin_amdgcn_sched_barrier(0);

#define EXITB()                      \
  __builtin_amdgcn_sched_barrier(0); \
  __builtin_amdgcn_s_barrier();      \
  __builtin_amdgcn_sched_barrier(0);

  // s = 0 (also drain scl ds_writes for all waves via lgkmcnt)
  asm volatile("s_waitcnt vmcnt(4) lgkmcnt(0)" ::: "memory");
  __builtin_amdgcn_s_barrier();
  __builtin_amdgcn_sched_barrier(0);
  COMPUTE(0);
  EXITB();
  STAGE(2);
  __builtin_amdgcn_sched_barrier(0);

  ENTRY("8") COMPUTE(1); EXITB(); STAGE(3); __builtin_amdgcn_sched_barrier(0);
  ENTRY("8") COMPUTE(2); EXITB(); STAGE(4); __builtin_amdgcn_sched_barrier(0);
  ENTRY("8") COMPUTE(3); EXITB(); STAGE(5); __builtin_amdgcn_sched_barrier(0);
  ENTRY("8") COMPUTE(4); EXITB(); STAGE(6); __builtin_amdgcn_sched_barrier(0);
  ENTRY("8") COMPUTE(5); EXITB(); STAGE(7); __builtin_amdgcn_sched_barrier(0);
  ENTRY("8") COMPUTE(6); EXITB();
  ENTRY("4") COMPUTE(7);

#undef ENTRY
#undef EXITB

  // ---- stats: lane owns channel wchan+l16; reduce over q4 groups (p).
  sacc += __shfl_xor(sacc, 16, 64);
  qacc += __shfl_xor(qacc, 16, 64);
  sacc += __shfl_xor(sacc, 32, 64);
  qacc += __shfl_xor(qacc, 32, 64);
  if (L < 16) {
    int slot = blockIdx.x & 31;
    atomicAdd(&ws[WS_PSUM + slot * 64 + wchan + l16], sacc);
    atomicAdd(&ws[WS_PSQ + slot * 64 + wchan + l16], qacc);
  }
}

// ---------------------------------------------------------------------------
// Kernel 3: in-place normalize + ReLU with inlined BN2 fold.
// ---------------------------------------------------------------------------
#define NORMB 4096
__global__ __launch_bounds__(256) void k_norm(float* __restrict__ out,
                                              const float* __restrict__ ws,
                                              const float* __restrict__ g_out,
                                              const float* __restrict__ b_out) {
  __shared__ float a2s[COUT], b2s[COUT];
  const int t = threadIdx.x;
  if (t < COUT) {
    float s = 0.f, q = 0.f;
#pragma unroll
    for (int sl = 0; sl < 32; ++sl) {
      s += ws[WS_PSUM + sl * 64 + t];
      q += ws[WS_PSQ + sl * 64 + t];
    }
    const float invP = 1.f / (float)PTOT;
    float mean = s * invP;
    float var = q * invP - mean * mean;
    float a = g_out[t] * rsqrtf(var + EPS);
    a2s[t] = a;
    b2s[t] = b_out[t] - a * mean;
  }
  __syncthreads();
  size_t i4 = (size_t)blockIdx.x * 256 + t;
  const size_t stride = (size_t)NORMB * 256;
  float4* p = (float4*)out;
#pragma unroll
  for (int it = 0; it < 8; ++it, i4 += stride) {
    int c = (int)((i4 >> 15) & 63);  // elem = i4*4; c = (elem>>17)&63
    float a = a2s[c];
    float bb = b2s[c];
    float4 v = p[i4];
    v.x = fmaxf(a * v.x + bb, 0.f);
    v.y = fmaxf(a * v.y + bb, 0.f);
    v.z = fmaxf(a * v.z + bb, 0.f);
    v.w = fmaxf(a * v.w + bb, 0.f);
    p[i4] = v;
  }
}

extern "C" void kernel_launch(void* const* d_in, const int* in_sizes, int n_in,
                              void* d_out, int out_size, void* d_ws,
                              size_t ws_size, hipStream_t stream) {
  const float* gx = (const float*)d_in[0];
  const float* feat = (const float*)d_in[1];
  const float* w1 = (const float*)d_in[2];
  const float* g1 = (const float*)d_in[3];
  const float* b1 = (const float*)d_in[4];
  const float* w2 = (const float*)d_in[5];
  const float* b2 = (const float*)d_in[6];
  const float* wb = (const float*)d_in[7];
  const float* g_out = (const float*)d_in[8];
  const float* b_out = (const float*)d_in[9];
  float* out = (float*)d_out;
  float* ws = (float*)d_ws;
  ushort16* wbt = (ushort16*)(ws + WS_WBT);

  (void)in_sizes; (void)n_in; (void)out_size; (void)ws_size;

  hipMemsetAsync(d_ws, 0, WS_ZERO_FLOATS * sizeof(float), stream);

  k_pre<<<MOMB + 128, 256, 0, stream>>>(gx, wb, ws);
  k_main_mfma<<<PTOT / PPB, 256, 0, stream>>>(gx, feat, w1, g1, b1, w2, b2,
                                              wbt, ws, out);
  k_norm<<<NORMB, 256, 0, stream>>>(out, ws, g_out, b_out);
}